// Round 5
// baseline (145.927 us; speedup 1.0000x reference)
//
#include <hip/hip_runtime.h>
#include <cfloat>

// Emu3 VQ-VAE vector quantizer argmin (exact-rounding match to numpy ref):
//   x [9216,4] f32 (channels-last gather from [1,4,4,48,48])
//   e [32768,4] f32
//   out[n] = argmin_k fl( fl(x2+e2) - 2*fl(dot) ), first-min tie semantics.
//
// Round 10 — transpose the parallelization (lanes = rows, codebook uniform):
//  - R5-R9 invariant at 78-84us across occupancy 26/47/35%, VGPR 32/64,
//    pk vs scalar, prefetch 1 vs 3 -> per-SIMD VALU-stream bound; the old
//    mapping pays e2 recompute + addressing + vmcnt on top of the 9-op floor.
//  - New mapping: each lane owns ONE row (x in 5 VGPRs); codebook + precomp
//    e2 table are wave-uniform -> s_load into SGPRs (SMEM co-issues free
//    with VALU). Hot loop = exactly 9 VALU per (row,entry): mul,3xfma,add,
//    fma,cmp,2xcndmask. No per-lane loads, no vmcnt in loop.
//  - Parallelism via 64 codebook segments x 36 row-groups = 2304 blocks;
//    cross-block argmin by atomicMin on u64 key bits(d)<<32|k. d>0 on this
//    data (d ~ ||x||^2 ~ 4) so f32 bit order = numeric order; (min d, min k)
//    == first-index tie-break EXACTLY (ties are common: e ~ 1e-5, distance
//    spread ~100s of ulps over 32768 candidates).
//  - fl sequences op-for-op identical to validated R8 kernel -> all rounded
//    distances bitwise unchanged; absmax must stay 0.
//  - Prologue kernel: e2 table (same fl chain) + key init (no memset in
//    graph capture). Epilogue kernel: key -> index.

#define NROWS 9216
#define NK    32768
#define RGSZ  256
#define NRG   (NROWS / RGSZ)   // 36 row groups (2304 = 9*256 -> no t straddle)
#define SEGS  64
#define SEGSZ (NK / SEGS)      // 512 entries per segment

__device__ __forceinline__ float sq4(float4 e) {
    return __fadd_rn(__fadd_rn(__fadd_rn(__fmul_rn(e.x, e.x),
                                         __fmul_rn(e.y, e.y)),
                               __fmul_rn(e.z, e.z)),
                     __fmul_rn(e.w, e.w));
}

__global__ __launch_bounds__(256)
void vq_prep(const float4* __restrict__ cb, float* __restrict__ e2t,
             unsigned long long* __restrict__ keys)
{
    int k = blockIdx.x * 256 + threadIdx.x;   // 32768 threads
    e2t[k] = sq4(cb[k]);
    if (k < NROWS) keys[k] = ~0ull;
}

__global__ __launch_bounds__(256)
void vq_main(const float* __restrict__ hs, const float4* __restrict__ cb,
             const float* __restrict__ e2t, unsigned long long* __restrict__ keys)
{
    const int rg  = blockIdx.x % NRG;
    const int seg = blockIdx.x / NRG;

    // Each thread owns one row. Rowgroups of 256 lie inside one t (2304=9*256)
    // -> the 4 channel loads are coalesced within the block.
    const int n   = rg * RGSZ + threadIdx.x;
    const int t   = n / 2304;                 // 2304 = 48*48
    const int rem = n - t * 2304;
    const float* p = hs + t * 9216 + rem;
    const float x0 = p[0], x1 = p[2304], x2 = p[4608], x3 = p[6912];
    const float xq = __fadd_rn(__fadd_rn(__fadd_rn(__fmul_rn(x0, x0),
                                                   __fmul_rn(x1, x1)),
                                         __fmul_rn(x2, x2)),
                               __fmul_rn(x3, x3));

    const int base = seg * SEGSZ;
    float best = FLT_MAX;
    int   bk   = 0;

    // Wave-uniform codebook/e2 reads -> SGPR buffers, ping-pong by 4 entries.
    float4 eA[4], eB[4];
    float  qA[4], qB[4];

    auto ldg = [&](float4* e, float* q, int jj) {
        int o = (base + jj) & (NK - 1);       // wrap keeps tail prefetch legal
        #pragma unroll
        for (int u = 0; u < 4; ++u) { e[u] = cb[o + u]; q[u] = e2t[o + u]; }
    };
    auto comp = [&](const float4* e, const float* q, int j0) {
        #pragma unroll
        for (int u = 0; u < 4; ++u) {
            float dot = __fmul_rn(x0, e[u].x);
            dot = __fmaf_rn(x1, e[u].y, dot);
            dot = __fmaf_rn(x2, e[u].z, dot);
            dot = __fmaf_rn(x3, e[u].w, dot);
            float t1 = __fadd_rn(xq, q[u]);
            float d  = __fmaf_rn(dot, -2.0f, t1);
            if (d < best) { best = d; bk = base + j0 + u; }   // strict < keeps
        }                                                     // earliest k
    };

    ldg(eA, qA, 0);
    for (int j = 0; j < SEGSZ; j += 8) {
        ldg(eB, qB, j + 4);
        comp(eA, qA, j);
        ldg(eA, qA, j + 8);                   // last iter: dummy wrap reload
        comp(eB, qB, j + 4);
    }

    // d > 0 on this data -> f32 bit pattern order == numeric order.
    // key = (bits(d) << 32) | k : global u64 min == (min d, then min k)
    // == reference first-min tie semantics.
    unsigned long long key =
        ((unsigned long long)__builtin_bit_cast(unsigned, best) << 32) |
        (unsigned)bk;
    atomicMin(keys + n, key);
}

__global__ __launch_bounds__(256)
void vq_extract(const unsigned long long* __restrict__ keys,
                int* __restrict__ out)
{
    int n = blockIdx.x * 256 + threadIdx.x;   // 9216 threads
    out[n] = (int)(keys[n] & 0xFFFFFFFFull);
}

extern "C" void kernel_launch(void* const* d_in, const int* in_sizes, int n_in,
                              void* d_out, int out_size, void* d_ws, size_t ws_size,
                              hipStream_t stream)
{
    const float*  hs = (const float*)d_in[0];    // [1,4,4,48,48]
    const float4* cb = (const float4*)d_in[1];   // [32768,4]
    int* out = (int*)d_out;                      // [9216] int32

    unsigned long long* keys = (unsigned long long*)d_ws;          // 72 KiB
    float* e2t = (float*)((char*)d_ws + NROWS * sizeof(unsigned long long));
                                                                   // 128 KiB

    vq_prep<<<NK / 256, 256, 0, stream>>>(cb, e2t, keys);
    vq_main<<<NRG * SEGS, 256, 0, stream>>>(hs, cb, e2t, keys);
    vq_extract<<<NROWS / 256, 256, 0, stream>>>(keys, out);
}